// Round 16
// baseline (550.050 us; speedup 1.0000x reference)
//
#include <hip/hip_runtime.h>
#include <hip/hip_bf16.h>
#include <math.h>

#define N_TOK 32768
#define DIMX 512
#define HEADS 8
#define DHEAD 64
#define ANUM 256
#define SCALE_Q 0.125f
#define KVCHUNK 1024
#define NCHUNK 32
#define STRIP 8192

typedef __bf16 v8bf __attribute__((ext_vector_type(8)));
typedef float v4f __attribute__((ext_vector_type(4)));
typedef unsigned short u16x8 __attribute__((ext_vector_type(8)));

typedef __attribute__((address_space(1))) const void gas_void;
typedef __attribute__((address_space(3))) void las_void;

__device__ __forceinline__ void gld16(const void* g, void* l) {
    __builtin_amdgcn_global_load_lds((gas_void*)g, (las_void*)l, 16, 0, 0);
}

__device__ inline unsigned short f2bf(float f) {   // RTNE
    unsigned u = __float_as_uint(f);
    return (unsigned short)((u + 0x7fffu + ((u >> 16) & 1u)) >> 16);
}
__device__ inline float bf2f(unsigned short s) {
    return __uint_as_float((unsigned)s << 16);
}

// ---------------- K0: fp32 -> 3-way bf16 split (hi, mid, lo), 8 elems/thread ----------------
__global__ __launch_bounds__(256) void k_cvt3(const float* __restrict__ src,
                                              unsigned short* __restrict__ ph,
                                              unsigned short* __restrict__ pm,
                                              unsigned short* __restrict__ pl,
                                              int n8) {
    for (int i = blockIdx.x * 256 + threadIdx.x; i < n8; i += gridDim.x * 256) {
        float4 a = ((const float4*)src)[2 * i];
        float4 b = ((const float4*)src)[2 * i + 1];
        float v[8] = {a.x, a.y, a.z, a.w, b.x, b.y, b.z, b.w};
        u16x8 H, M, L;
        #pragma unroll
        for (int j = 0; j < 8; ++j) {
            unsigned short h = f2bf(v[j]);
            float r1 = v[j] - bf2f(h);
            unsigned short m = f2bf(r1);
            float r2 = r1 - bf2f(m);
            H[j] = h; M[j] = m; L[j] = f2bf(r2);
        }
        ((u16x8*)ph)[i] = H;
        ((u16x8*)pm)[i] = M;
        ((u16x8*)pl)[i] = L;
    }
}

// ---------------- K1: strip GEMM, split-bf16 MFMA + global_load_lds + XCD swizzle ----------------
__global__ __launch_bounds__(256, 2) void k_gemm(
        const unsigned short* __restrict__ xh, const unsigned short* __restrict__ xm,
        const unsigned short* __restrict__ xl,
        const unsigned short* __restrict__ wh, const unsigned short* __restrict__ wm,
        const unsigned short* __restrict__ wl,
        unsigned short* __restrict__ qb, float* __restrict__ kvb,
        unsigned short* __restrict__ vhg, unsigned short* __restrict__ vmg, int mbase) {
    __shared__ __align__(16) unsigned short lds[6 * 4096];
    unsigned short* Ah = lds;
    unsigned short* Am = lds + 4096;
    unsigned short* Al = lds + 8192;
    unsigned short* Bh = lds + 12288;
    unsigned short* Bm = lds + 16384;
    unsigned short* Bl = lds + 20480;
    const int tid = threadIdx.x;
    const int lane = tid & 63;
    const int wid = tid >> 6;
    const int wr = wid >> 1;
    const int wc = wid & 1;
    const int lin = blockIdx.x;
    const int swz = (lin & 7) * 96 + (lin >> 3);
    const int mloc0 = (swz / 12) * 128;
    const int j0 = (swz % 12) * 128;
    const bool isQ = (j0 < 512);
#define SWZ(row, ks) ((row) * 64 + (((ks) ^ (((row) >> 1) & 3)) << 4))
    const int srow0 = tid >> 2;
    const int srow1 = srow0 + 64;
    const int ksw = tid & 3;
    const int ks0 = ksw ^ ((srow0 >> 1) & 3);
    const int ks1 = ksw ^ ((srow1 >> 1) & 3);
    const size_t ga0 = (size_t)(mloc0 + srow0) * DIMX + ks0 * 8;
    const size_t ga1 = (size_t)(mloc0 + srow1) * DIMX + ks1 * 8;
    const size_t gb0 = (size_t)(j0 + srow0) * DIMX + ks0 * 8;
    const size_t gb1 = (size_t)(j0 + srow1) * DIMX + ks1 * 8;
    const int lo0 = tid * 16;
    const int lo1 = 4096 + tid * 16;

    v4f acc[4][4];
    #pragma unroll
    for (int i = 0; i < 4; ++i)
        #pragma unroll
        for (int j = 0; j < 4; ++j)
            #pragma unroll
            for (int r = 0; r < 4; ++r) acc[i][j][r] = 0.0f;

    const int fm = lane & 15;
    const int fks = lane >> 4;
    int aofs[4], bofs[4];
    #pragma unroll
    for (int i = 0; i < 4; ++i) {
        const int am = wr * 64 + i * 16 + fm;
        const int bm = wc * 64 + i * 16 + fm;
        aofs[i] = SWZ(am, fks);
        bofs[i] = SWZ(bm, fks);
    }
#undef SWZ

    for (int k0 = 0; k0 < DIMX; k0 += 32) {
        __syncthreads();
        gld16(xh + ga0 + k0, (char*)Ah + lo0);
        gld16(xh + ga1 + k0, (char*)Ah + lo1);
        gld16(xm + ga0 + k0, (char*)Am + lo0);
        gld16(xm + ga1 + k0, (char*)Am + lo1);
        gld16(wh + gb0 + k0, (char*)Bh + lo0);
        gld16(wh + gb1 + k0, (char*)Bh + lo1);
        gld16(wm + gb0 + k0, (char*)Bm + lo0);
        gld16(wm + gb1 + k0, (char*)Bm + lo1);
        if (!isQ) {
            gld16(xl + ga0 + k0, (char*)Al + lo0);
            gld16(xl + ga1 + k0, (char*)Al + lo1);
            gld16(wl + gb0 + k0, (char*)Bl + lo0);
            gld16(wl + gb1 + k0, (char*)Bl + lo1);
        }
        __syncthreads();
        v8bf fah[4], fbh[4];
        #pragma unroll
        for (int i = 0; i < 4; ++i) {
            fah[i] = *(const v8bf*)((const char*)Ah + aofs[i]);
            fbh[i] = *(const v8bf*)((const char*)Bh + bofs[i]);
        }
        #pragma unroll
        for (int mi = 0; mi < 4; ++mi)
            #pragma unroll
            for (int ni = 0; ni < 4; ++ni)
                acc[mi][ni] = __builtin_amdgcn_mfma_f32_16x16x32_bf16(fah[mi], fbh[ni], acc[mi][ni], 0, 0, 0);
        v8bf fam[4], fbm[4];
        #pragma unroll
        for (int i = 0; i < 4; ++i) {
            fam[i] = *(const v8bf*)((const char*)Am + aofs[i]);
            fbm[i] = *(const v8bf*)((const char*)Bm + bofs[i]);
        }
        #pragma unroll
        for (int mi = 0; mi < 4; ++mi)
            #pragma unroll
            for (int ni = 0; ni < 4; ++ni) {
                acc[mi][ni] = __builtin_amdgcn_mfma_f32_16x16x32_bf16(fah[mi], fbm[ni], acc[mi][ni], 0, 0, 0);
                acc[mi][ni] = __builtin_amdgcn_mfma_f32_16x16x32_bf16(fam[mi], fbh[ni], acc[mi][ni], 0, 0, 0);
            }
        if (!isQ) {
            #pragma unroll
            for (int mi = 0; mi < 4; ++mi)
                #pragma unroll
                for (int ni = 0; ni < 4; ++ni)
                    acc[mi][ni] = __builtin_amdgcn_mfma_f32_16x16x32_bf16(fam[mi], fbm[ni], acc[mi][ni], 0, 0, 0);
            v8bf fal[4], fbl[4];
            #pragma unroll
            for (int i = 0; i < 4; ++i) {
                fal[i] = *(const v8bf*)((const char*)Al + aofs[i]);
                fbl[i] = *(const v8bf*)((const char*)Bl + bofs[i]);
            }
            #pragma unroll
            for (int mi = 0; mi < 4; ++mi)
                #pragma unroll
                for (int ni = 0; ni < 4; ++ni) {
                    acc[mi][ni] = __builtin_amdgcn_mfma_f32_16x16x32_bf16(fah[mi], fbl[ni], acc[mi][ni], 0, 0, 0);
                    acc[mi][ni] = __builtin_amdgcn_mfma_f32_16x16x32_bf16(fal[mi], fbh[ni], acc[mi][ni], 0, 0, 0);
                }
        }
    }
    const int crow = (lane >> 4) * 4;
    const int ccol = lane & 15;
    if (isQ) {
        #pragma unroll
        for (int mi = 0; mi < 4; ++mi)
            #pragma unroll
            for (int ni = 0; ni < 4; ++ni) {
                const int j = j0 + wc * 64 + ni * 16 + ccol;
                #pragma unroll
                for (int r = 0; r < 4; ++r) {
                    const int m = mbase + mloc0 + wr * 64 + mi * 16 + crow + r;
                    qb[(size_t)m * DIMX + j] = f2bf(acc[mi][ni][r]);
                }
            }
    } else if (j0 < 1024) {  // k -> fp32 [N][512]
        #pragma unroll
        for (int mi = 0; mi < 4; ++mi)
            #pragma unroll
            for (int ni = 0; ni < 4; ++ni) {
                const int j = j0 - 512 + wc * 64 + ni * 16 + ccol;
                #pragma unroll
                for (int r = 0; r < 4; ++r) {
                    const int m = mbase + mloc0 + wr * 64 + mi * 16 + crow + r;
                    kvb[(size_t)m * 512 + j] = acc[mi][ni][r];
                }
            }
    } else {                 // v -> hi/mid bf16 [N][512]
        #pragma unroll
        for (int mi = 0; mi < 4; ++mi)
            #pragma unroll
            for (int ni = 0; ni < 4; ++ni) {
                const int j = j0 - 1024 + wc * 64 + ni * 16 + ccol;
                #pragma unroll
                for (int r = 0; r < 4; ++r) {
                    const int m = mbase + mloc0 + wr * 64 + mi * 16 + crow + r;
                    const float val = acc[mi][ni][r];
                    const unsigned short hb = f2bf(val);
                    vhg[(size_t)m * 512 + j] = hb;
                    vmg[(size_t)m * 512 + j] = f2bf(val - bf2f(hb));
                }
            }
    }
}

// ---------------- K2: MFMA kv-aggregation (r7/r12 version) ----------------
__global__ __launch_bounds__(512, 1) void k_kvagg(
        const float* __restrict__ kvb,
        const unsigned short* __restrict__ vhg, const unsigned short* __restrict__ vmg,
        const unsigned short* __restrict__ agh, const unsigned short* __restrict__ agm,
        const unsigned short* __restrict__ agl,
        float* __restrict__ pacc, float* __restrict__ psum) {
    __shared__ __align__(16) char S[61440];
    const int h = blockIdx.x, chunk = blockIdx.y;
    const int t = threadIdx.x, lane = t & 63, w = t >> 6;
    const int fr = lane & 15, fc = lane >> 4;
    const int n0 = chunk * KVCHUNK;
    v8bf agf[3][2][2];
    #pragma unroll
    for (int mt = 0; mt < 2; ++mt)
        #pragma unroll
        for (int ks = 0; ks < 2; ++ks) {
            const size_t ix = ((size_t)(h * ANUM + w * 32 + mt * 16 + fr)) * 64 + ks * 32 + fc * 8;
            agf[0][mt][ks] = *(const v8bf*)(agh + ix);
            agf[1][mt][ks] = *(const v8bf*)(agm + ix);
            agf[2][mt][ks] = *(const v8bf*)(agl + ix);
        }
    const int cn = t >> 4;
    const int cd0 = (t & 15) * 4;
    float4 kreg; ushort4 vhr, vmr;
    {
        const size_t gix = ((size_t)(n0 + cn)) * 512 + h * 64 + cd0;
        kreg = *(const float4*)(kvb + gix);
        vhr = *(const ushort4*)(vhg + gix);
        vmr = *(const ushort4*)(vmg + gix);
    }
    v4f kvacc[2][4];
    #pragma unroll
    for (int mt = 0; mt < 2; ++mt)
        #pragma unroll
        for (int nt = 0; nt < 4; ++nt)
            #pragma unroll
            for (int r = 0; r < 4; ++r) kvacc[mt][nt][r] = 0.f;
    float sacc[2][4] = {{0.f,0.f,0.f,0.f},{0.f,0.f,0.f,0.f}};

    for (int it = 0; it < 32; ++it) {
        __syncthreads();
        {
            ushort4 H, M, L;
            unsigned short hh;
            hh = f2bf(kreg.x); { float r1 = kreg.x - bf2f(hh); M.x = f2bf(r1);
                L.x = f2bf(r1 - bf2f(M.x)); H.x = hh; }
            hh = f2bf(kreg.y); { float r1 = kreg.y - bf2f(hh); M.y = f2bf(r1);
                L.y = f2bf(r1 - bf2f(M.y)); H.y = hh; }
            hh = f2bf(kreg.z); { float r1 = kreg.z - bf2f(hh); M.z = f2bf(r1);
                L.z = f2bf(r1 - bf2f(M.z)); H.z = hh; }
            hh = f2bf(kreg.w); { float r1 = kreg.w - bf2f(hh); M.w = f2bf(r1);
                L.w = f2bf(r1 - bf2f(M.w)); H.w = hh; }
            const int kb0 = cn * 128 + ((cd0 * 2) ^ ((cn & 7) << 4));
            *(ushort4*)(S + kb0) = H;
            *(ushort4*)(S + 4096 + kb0) = M;
            *(ushort4*)(S + 8192 + kb0) = L;
            const unsigned short vh4[4] = {vhr.x, vhr.y, vhr.z, vhr.w};
            const unsigned short vm4[4] = {vmr.x, vmr.y, vmr.z, vmr.w};
            #pragma unroll
            for (int i = 0; i < 4; ++i) {
                const int d = cd0 + i;
                const int vb = d * 128 + ((cn * 2) ^ ((d & 7) << 4));
                *(unsigned short*)(S + 12288 + vb) = vh4[i];
                *(unsigned short*)(S + 20480 + vb) = vm4[i];
            }
        }
        if (it < 31) {
            const size_t gix = ((size_t)(n0 + (it + 1) * 32 + cn)) * 512 + h * 64 + cd0;
            kreg = *(const float4*)(kvb + gix);
            vhr = *(const ushort4*)(vhg + gix);
            vmr = *(const ushort4*)(vmg + gix);
        }
        __syncthreads();
        v4f C[2][2];
        #pragma unroll
        for (int mt = 0; mt < 2; ++mt)
            #pragma unroll
            for (int nt = 0; nt < 2; ++nt)
                #pragma unroll
                for (int r = 0; r < 4; ++r) C[mt][nt][r] = 0.f;
        #pragma unroll
        for (int ks = 0; ks < 2; ++ks) {
            v8bf kb[3][2];
            #pragma unroll
            for (int nt = 0; nt < 2; ++nt) {
                const int row = nt * 16 + fr;
                const int off = row * 128 + ((ks * 64 + fc * 16) ^ ((row & 7) << 4));
                kb[0][nt] = *(const v8bf*)(S + off);
                kb[1][nt] = *(const v8bf*)(S + 4096 + off);
                kb[2][nt] = *(const v8bf*)(S + 8192 + off);
            }
            #pragma unroll
            for (int mt = 0; mt < 2; ++mt)
                #pragma unroll
                for (int nt = 0; nt < 2; ++nt) {
                    C[mt][nt] = __builtin_amdgcn_mfma_f32_16x16x32_bf16(agf[0][mt][ks], kb[0][nt], C[mt][nt], 0, 0, 0);
                    C[mt][nt] = __builtin_amdgcn_mfma_f32_16x16x32_bf16(agf[0][mt][ks], kb[1][nt], C[mt][nt], 0, 0, 0);
                    C[mt][nt] = __builtin_amdgcn_mfma_f32_16x16x32_bf16(agf[1][mt][ks], kb[0][nt], C[mt][nt], 0, 0, 0);
                    C[mt][nt] = __builtin_amdgcn_mfma_f32_16x16x32_bf16(agf[1][mt][ks], kb[1][nt], C[mt][nt], 0, 0, 0);
                    C[mt][nt] = __builtin_amdgcn_mfma_f32_16x16x32_bf16(agf[0][mt][ks], kb[2][nt], C[mt][nt], 0, 0, 0);
                    C[mt][nt] = __builtin_amdgcn_mfma_f32_16x16x32_bf16(agf[2][mt][ks], kb[0][nt], C[mt][nt], 0, 0, 0);
                }
        }
        const int pbase = 28672 + w * 4096;
        #pragma unroll
        for (int mt = 0; mt < 2; ++mt) {
            float sl[4] = {0.f, 0.f, 0.f, 0.f};
            #pragma unroll
            for (int nt = 0; nt < 2; ++nt)
                #pragma unroll
                for (int r = 0; r < 4; ++r) {
                    const float pv = __expf(C[mt][nt][r] - 20.f);
                    sl[r] += pv;
                    const unsigned short ph = f2bf(pv);
                    const unsigned short pmv = f2bf(pv - bf2f(ph));
                    const int a = mt * 16 + fc * 4 + r;
                    const int off = pbase + a * 64 + (((nt * 16 + fr) * 2) ^ ((a & 3) << 4));
                    *(unsigned short*)(S + off) = ph;
                    *(unsigned short*)(S + off + 2048) = pmv;
                }
            #pragma unroll
            for (int r = 0; r < 4; ++r) {
                float v = sl[r];
                v += __shfl_xor(v, 1, 64); v += __shfl_xor(v, 2, 64);
                v += __shfl_xor(v, 4, 64); v += __shfl_xor(v, 8, 64);
                sacc[mt][r] += v;
            }
        }
        v8bf pah[2], pam[2];
        #pragma unroll
        for (int mt = 0; mt < 2; ++mt) {
            const int a = mt * 16 + fr;
            const int off = pbase + a * 64 + ((fc * 16) ^ ((a & 3) << 4));
            pah[mt] = *(const v8bf*)(S + off);
            pam[mt] = *(const v8bf*)(S + off + 2048);
        }
        #pragma unroll
        for (int nt = 0; nt < 4; ++nt) {
            const int d = nt * 16 + fr;
            const int off = 12288 + d * 128 + ((fc * 16) ^ ((d & 7) << 4));
            v8bf vbh = *(const v8bf*)(S + off);
            v8bf vbm = *(const v8bf*)(S + off + 8192);
            #pragma unroll
            for (int mt = 0; mt < 2; ++mt) {
                kvacc[mt][nt] = __builtin_amdgcn_mfma_f32_16x16x32_bf16(pah[mt], vbh, kvacc[mt][nt], 0, 0, 0);
                kvacc[mt][nt] = __builtin_amdgcn_mfma_f32_16x16x32_bf16(pah[mt], vbm, kvacc[mt][nt], 0, 0, 0);
                kvacc[mt][nt] = __builtin_amdgcn_mfma_f32_16x16x32_bf16(pam[mt], vbh, kvacc[mt][nt], 0, 0, 0);
                kvacc[mt][nt] = __builtin_amdgcn_mfma_f32_16x16x32_bf16(pam[mt], vbm, kvacc[mt][nt], 0, 0, 0);
            }
        }
    }
    const size_t base = (size_t)chunk * HEADS + h;
    #pragma unroll
    for (int mt = 0; mt < 2; ++mt)
        #pragma unroll
        for (int r = 0; r < 4; ++r)
            if (fr == 0)
                psum[base * ANUM + w * 32 + mt * 16 + fc * 4 + r] = sacc[mt][r];
    #pragma unroll
    for (int mt = 0; mt < 2; ++mt)
        #pragma unroll
        for (int nt = 0; nt < 4; ++nt)
            #pragma unroll
            for (int r = 0; r < 4; ++r)
                pacc[base * (ANUM * DHEAD) +
                     (size_t)(w * 32 + mt * 16 + fc * 4 + r) * 64 + nt * 16 + fr] =
                    kvacc[mt][nt][r];
}

// ---------------- K2b: combine chunk partials -> kv[h,a,d] ----------------
__global__ __launch_bounds__(256) void k_combine(const float* __restrict__ pacc,
                                                 const float* __restrict__ psum,
                                                 float* __restrict__ kv) {
    const int idx = blockIdx.x * 256 + threadIdx.x;
    const int ha = idx >> 6;
    float a = 0.f, s = 0.f;
    for (int c = 0; c < NCHUNK; ++c) {
        a += pacc[(size_t)c*131072 + idx];
        s += psum[c*2048 + ha];
    }
    kv[idx] = a / s;
}

// ---------------- K3a: partial dot products for thresh (128 blocks) ----------------
__global__ __launch_bounds__(256) void k_thresh_part(const float* __restrict__ kv,
                                                     const float* __restrict__ Wt,
                                                     float* __restrict__ part) {
    __shared__ float red[256];
    const int t = threadIdx.x;
    const int base = blockIdx.x * 1024 + t * 4;
    float4 kvv = *(const float4*)&kv[base];
    float4 wv  = *(const float4*)&Wt[base & (DIMX - 1)];
    red[t] = kvv.x * wv.x + kvv.y * wv.y + kvv.z * wv.z + kvv.w * wv.w;
    __syncthreads();
    for (int off = 128; off > 0; off >>= 1) {
        if (t < off) red[t] += red[t + off];
        __syncthreads();
    }
    if (t == 0) part[blockIdx.x] = red[0];
}

// ---------------- K3b: finalize thresh = sigmoid(sum/256 + bt) ----------------
__global__ __launch_bounds__(128) void k_thresh_fin(const float* __restrict__ part,
                                                    const float* __restrict__ bt,
                                                    float* __restrict__ th) {
    __shared__ float red[128];
    const int t = threadIdx.x;
    red[t] = part[t];
    __syncthreads();
    for (int off = 64; off > 0; off >>= 1) {
        if (t < off) red[t] += red[t + off];
        __syncthreads();
    }
    if (t == 0) {
        float m = red[0] / (float)ANUM + bt[0];
        th[0] = 1.f / (1.f + expf(-m));
    }
}

// ---------------- K4: gating + row softmax; writes TRANSPOSED split kvf ----------------
__global__ __launch_bounds__(64) void k_gate(const float* __restrict__ kv,
                                             const float* __restrict__ Wn,
                                             const float* __restrict__ bn,
                                             const float* __restrict__ Wm,
                                             const float* __restrict__ bm,
                                             const float* __restrict__ th,
                                             unsigned short* __restrict__ kth,
                                             unsigned short* __restrict__ ktm) {
    const int rowi = blockIdx.x;     // h*256+a
    const int d = threadIdx.x;
    __shared__ __align__(16) float r[64];
    r[d] = kv[(size_t)rowi*64 + d];
    __syncthreads();
    float sn = bn[d], sm = bm[d];
    #pragma unroll
    for (int j4 = 0; j4 < 16; ++j4) {
        float4 rr = *(const float4*)&r[j4*4];
        float4 w1 = *(const float4*)&Wn[d*64 + j4*4];
        float4 w2 = *(const float4*)&Wm[d*64 + j4*4];
        sn += rr.x*w1.x + rr.y*w1.y + rr.z*w1.z + rr.w*w1.w;
        sm += rr.x*w2.x + rr.y*w2.y + rr.z*w2.z + rr.w*w2.w;
    }
    float noise = 1.f/(1.f + __expf(-sn));
    float maskv = 1.f/(1.f + __expf(-sm));
    float tval = th[0];
    float val = r[d] * (maskv > tval ? 1.f : 0.f) + noise;
    float m = val;
    #pragma unroll
    for (int off = 32; off > 0; off >>= 1) m = fmaxf(m, __shfl_xor(m, off, 64));
    float e = __expf(val - m);
    float ssum = e;
    #pragma unroll
    for (int off = 32; off > 0; off >>= 1) ssum += __shfl_xor(ssum, off, 64);
    const float res = e / ssum;
    const int hh = rowi >> 8;
    const int a  = rowi & 255;
    unsigned short hb = f2bf(res);
    const size_t tix = ((size_t)hh * DHEAD + d) * ANUM + a;
    kth[tix] = hb;
    ktm[tix] = f2bf(res - bf2f(hb));
}

// ---------------- K5: out via MFMA; PV by d-columns + T14 issue-early PV B-loads ----------------
// PV B-frags (kth/ktm, depend only on dcol) are loaded at kernel entry so their
// L2 latency hides under the S phase + softmax. Same MFMA order -> bit-identical.
__global__ __launch_bounds__(256, 4) void k_out_mfma(
        const unsigned short* __restrict__ qb,
        const unsigned short* __restrict__ agh, const unsigned short* __restrict__ agm,
        const unsigned short* __restrict__ kth, const unsigned short* __restrict__ ktm,
        float* __restrict__ out) {
    __shared__ __align__(16) unsigned short P[64 * 256];    // [tok][agent] swizzled, 32KB
    __shared__ float s_red[4][64];
    const int t = threadIdx.x;
    const int lane = t & 63;
    const int w = t >> 6;
    const int h = blockIdx.y;
    const int n0 = blockIdx.x * 64;
    const int fr = lane & 15;
    const int fc = lane >> 4;
    const int dcol = w * 16 + fr;
    // T14: issue PV B-frag loads NOW; they complete during the S phase.
    v8bf vfh[8], vfm[8];
    #pragma unroll
    for (int ks = 0; ks < 8; ++ks) {
        const size_t bix = ((size_t)h * DHEAD + dcol) * ANUM + fc * 8 + ks * 32;
        vfh[ks] = *(const v8bf*)(kth + bix);
        vfm[ks] = *(const v8bf*)(ktm + bix);
    }
    v8bf qa[4][2];
    #pragma unroll
    for (int mt = 0; mt < 4; ++mt) {
        const unsigned short* qp = qb + (size_t)(n0 + mt * 16 + fr) * DIMX + h * DHEAD + fc * 8;
        qa[mt][0] = *(const v8bf*)qp;
        qa[mt][1] = *(const v8bf*)(qp + 32);
    }
    v4f C[4][4];
    #pragma unroll
    for (int i = 0; i < 4; ++i)
        #pragma unroll
        for (int j = 0; j < 4; ++j)
            #pragma unroll
            for (int r = 0; r < 4; ++r) C[i][j][r] = 0.f;
    const int a0w = w * 64;
    __builtin_amdgcn_s_setprio(1);
    #pragma unroll
    for (int nt = 0; nt < 4; ++nt) {
        const size_t bix = ((size_t)h * ANUM + a0w + nt * 16 + fr) * DHEAD + fc * 8;
        v8bf B0h = *(const v8bf*)(agh + bix);
        v8bf B1h = *(const v8bf*)(agh + bix + 32);
        v8bf B0m = *(const v8bf*)(agm + bix);
        v8bf B1m = *(const v8bf*)(agm + bix + 32);
        #pragma unroll
        for (int mt = 0; mt < 4; ++mt) {
            C[mt][nt] = __builtin_amdgcn_mfma_f32_16x16x32_bf16(qa[mt][0], B0h, C[mt][nt], 0, 0, 0);
            C[mt][nt] = __builtin_amdgcn_mfma_f32_16x16x32_bf16(qa[mt][1], B1h, C[mt][nt], 0, 0, 0);
            C[mt][nt] = __builtin_amdgcn_mfma_f32_16x16x32_bf16(qa[mt][0], B0m, C[mt][nt], 0, 0, 0);
            C[mt][nt] = __builtin_amdgcn_mfma_f32_16x16x32_bf16(qa[mt][1], B1m, C[mt][nt], 0, 0, 0);
        }
    }
    __builtin_amdgcn_s_setprio(0);
    #pragma unroll
    for (int mt = 0; mt < 4; ++mt)
        #pragma unroll
        for (int r = 0; r < 4; ++r) {
            const int tok = mt * 16 + fc * 4 + r;
            const int sw = (tok & 7) << 4;
            float pv[4];
            float sloc = 0.f;
            #pragma unroll
            for (int nt = 0; nt < 4; ++nt) {
                pv[nt] = __expf(C[mt][nt][r] * SCALE_Q);
                sloc += pv[nt];
            }
            #pragma unroll
            for (int m = 1; m < 16; m <<= 1) sloc += __shfl_xor(sloc, m, 64);
            if (fr == 0) s_red[w][tok] = sloc;
            #pragma unroll
            for (int nt = 0; nt < 4; ++nt) {
                const int ag = a0w + nt * 16 + fr;
                *(unsigned short*)((char*)P + ((tok * 512 + ag * 2) ^ sw)) = f2bf(pv[nt]);
            }
        }
    __syncthreads();
    v4f D[4];
    #pragma unroll
    for (int tg = 0; tg < 4; ++tg)
        #pragma unroll
        for (int r = 0; r < 4; ++r) D[tg][r] = 0.f;
    __builtin_amdgcn_s_setprio(1);
    #pragma unroll
    for (int ks = 0; ks < 8; ++ks) {
        #pragma unroll
        for (int tg = 0; tg < 4; ++tg) {
            const int tok = tg * 16 + fr;
            const int sw = (tok & 7) << 4;
            v8bf pa = *(const v8bf*)((const char*)P + ((tok * 512 + fc * 16 + ks * 64) ^ sw));
            D[tg] = __builtin_amdgcn_mfma_f32_16x16x32_bf16(pa, vfh[ks], D[tg], 0, 0, 0);
            D[tg] = __builtin_amdgcn_mfma_f32_16x16x32_bf16(pa, vfm[ks], D[tg], 0, 0, 0);
        }
    }
    __builtin_amdgcn_s_setprio(0);
    #pragma unroll
    for (int tg = 0; tg < 4; ++tg)
        #pragma unroll
        for (int r = 0; r < 4; ++r) {
            const int tok = tg * 16 + fc * 4 + r;
            const float inv = 1.f / (s_red[0][tok] + s_red[1][tok] + s_red[2][tok] + s_red[3][tok]);
            out[(size_t)(n0 + tok) * DIMX + h * DHEAD + dcol] = D[tg][r] * inv;
        }
}

extern "C" void kernel_launch(void* const* d_in, const int* in_sizes, int n_in,
                              void* d_out, int out_size, void* d_ws, size_t ws_size,
                              hipStream_t stream) {
    const float* x     = (const float*)d_in[0];
    const float* Wqkv  = (const float*)d_in[1];
    const float* agent = (const float*)d_in[2];
    const float* Wn    = (const float*)d_in[3];
    const float* bn    = (const float*)d_in[4];
    const float* Wm    = (const float*)d_in[5];
    const float* bm    = (const float*)d_in[6];
    const float* Wt    = (const float*)d_in[7];
    const float* bt    = (const float*)d_in[8];
    float* out = (float*)d_out;

    const size_t KB_F  = (size_t)N_TOK * 512;         // k fp32
    const size_t VB_E  = (size_t)N_TOK * 512;         // v bf16 per split
    const size_t QB_E  = (size_t)N_TOK * DIMX;
    const size_t WSP_E = (size_t)3 * DIMX * DIMX;
    const size_t XSP_E = (size_t)STRIP * DIMX;
    const size_t PACC_F = (size_t)NCHUNK * HEADS * ANUM * DHEAD;
    const size_t PSUM_F = (size_t)NCHUNK * HEADS * ANUM;
    const size_t KV_F   = (size_t)HEADS * ANUM * DHEAD;   // 131072

    char* p = (char*)d_ws;
    float* kvb = (float*)p;            p += KB_F * 4;
    unsigned short* vhg = (unsigned short*)p;  p += VB_E * 2;
    unsigned short* vmg = (unsigned short*)p;  p += VB_E * 2;
    unsigned short* qbuf = (unsigned short*)p; p += QB_E * 2;
    unsigned short* wh = (unsigned short*)p;   p += WSP_E * 2;
    unsigned short* wm = (unsigned short*)p;   p += WSP_E * 2;
    unsigned short* wl = (unsigned short*)p;   p += WSP_E * 2;
    unsigned short* xh = (unsigned short*)p;   p += XSP_E * 2;
    unsigned short* xm = (unsigned short*)p;   p += XSP_E * 2;
    unsigned short* xl = (unsigned short*)p;   p += XSP_E * 2;
    float* pacc = (float*)p;           p += PACC_F * 4;
    float* psum = (float*)p;           p += PSUM_F * 4;
    float* kv   = (float*)p;           p += KV_F * 4;
    unsigned short* agh = (unsigned short*)p;  p += KV_F * 2;
    unsigned short* agm = (unsigned short*)p;  p += KV_F * 2;
    unsigned short* agl = (unsigned short*)p;  p += KV_F * 2;
    unsigned short* kth = (unsigned short*)p;  p += KV_F * 2;
    unsigned short* ktm = (unsigned short*)p;  p += KV_F * 2;
    float* th   = (float*)p;           p += 64;
    float* thpart = (float*)p;         p += 128 * 4;
    if (ws_size < (size_t)(p - (char*)d_ws)) return;

    k_cvt3<<<384, 256, 0, stream>>>(Wqkv, wh, wm, wl, (int)(WSP_E / 8));
    k_cvt3<<<64, 256, 0, stream>>>(agent, agh, agm, agl, (int)(KV_F / 8));
    for (int s = 0; s < N_TOK / STRIP; ++s) {
        k_cvt3<<<2048, 256, 0, stream>>>(x + (size_t)s * STRIP * DIMX, xh, xm, xl,
                                         (int)(XSP_E / 8));
        k_gemm<<<768, 256, 0, stream>>>(xh, xm, xl, wh, wm, wl,
                                        qbuf, kvb, vhg, vmg, s * STRIP);
    }
    k_kvagg <<<dim3(HEADS, NCHUNK), 512, 0, stream>>>(kvb, vhg, vmg, agh, agm, agl,
                                                      pacc, psum);
    k_combine<<<512, 256, 0, stream>>>(pacc, psum, kv);
    k_thresh_part<<<128, 256, 0, stream>>>(kv, Wt, thpart);
    k_thresh_fin<<<1, 128, 0, stream>>>(thpart, bt, th);
    k_gate  <<<HEADS*ANUM, 64, 0, stream>>>(kv, Wn, bn, Wm, bm, th, kth, ktm);
    k_out_mfma<<<dim3(N_TOK/64, HEADS), 256, 0, stream>>>(qbuf, agh, agm, kth, ktm, out);
}

// Round 17
// 500.649 us; speedup vs baseline: 1.0987x; 1.0987x over previous
//
#include <hip/hip_runtime.h>
#include <hip/hip_bf16.h>
#include <math.h>

#define N_TOK 32768
#define DIMX 512
#define HEADS 8
#define DHEAD 64
#define ANUM 256
#define SCALE_Q 0.125f
#define KVCHUNK 1024
#define NCHUNK 32
#define STRIP 8192

typedef __bf16 v8bf __attribute__((ext_vector_type(8)));
typedef float v4f __attribute__((ext_vector_type(4)));
typedef unsigned short u16x8 __attribute__((ext_vector_type(8)));

typedef __attribute__((address_space(1))) const void gas_void;
typedef __attribute__((address_space(3))) void las_void;

__device__ __forceinline__ void gld16(const void* g, void* l) {
    __builtin_amdgcn_global_load_lds((gas_void*)g, (las_void*)l, 16, 0, 0);
}

__device__ inline unsigned short f2bf(float f) {   // RTNE
    unsigned u = __float_as_uint(f);
    return (unsigned short)((u + 0x7fffu + ((u >> 16) & 1u)) >> 16);
}
__device__ inline float bf2f(unsigned short s) {
    return __uint_as_float((unsigned)s << 16);
}

// ---------------- K0: fp32 -> 3-way bf16 split (hi, mid, lo), 8 elems/thread ----------------
__global__ __launch_bounds__(256) void k_cvt3(const float* __restrict__ src,
                                              unsigned short* __restrict__ ph,
                                              unsigned short* __restrict__ pm,
                                              unsigned short* __restrict__ pl,
                                              int n8) {
    for (int i = blockIdx.x * 256 + threadIdx.x; i < n8; i += gridDim.x * 256) {
        float4 a = ((const float4*)src)[2 * i];
        float4 b = ((const float4*)src)[2 * i + 1];
        float v[8] = {a.x, a.y, a.z, a.w, b.x, b.y, b.z, b.w};
        u16x8 H, M, L;
        #pragma unroll
        for (int j = 0; j < 8; ++j) {
            unsigned short h = f2bf(v[j]);
            float r1 = v[j] - bf2f(h);
            unsigned short m = f2bf(r1);
            float r2 = r1 - bf2f(m);
            H[j] = h; M[j] = m; L[j] = f2bf(r2);
        }
        ((u16x8*)ph)[i] = H;
        ((u16x8*)pm)[i] = M;
        ((u16x8*)pl)[i] = L;
    }
}

// ---------------- K1: strip GEMM, split-bf16 MFMA + global_load_lds + XCD swizzle ----------------
__global__ __launch_bounds__(256, 2) void k_gemm(
        const unsigned short* __restrict__ xh, const unsigned short* __restrict__ xm,
        const unsigned short* __restrict__ xl,
        const unsigned short* __restrict__ wh, const unsigned short* __restrict__ wm,
        const unsigned short* __restrict__ wl,
        unsigned short* __restrict__ qb, float* __restrict__ kvb,
        unsigned short* __restrict__ vhg, unsigned short* __restrict__ vmg, int mbase) {
    __shared__ __align__(16) unsigned short lds[6 * 4096];
    unsigned short* Ah = lds;
    unsigned short* Am = lds + 4096;
    unsigned short* Al = lds + 8192;
    unsigned short* Bh = lds + 12288;
    unsigned short* Bm = lds + 16384;
    unsigned short* Bl = lds + 20480;
    const int tid = threadIdx.x;
    const int lane = tid & 63;
    const int wid = tid >> 6;
    const int wr = wid >> 1;
    const int wc = wid & 1;
    const int lin = blockIdx.x;
    const int swz = (lin & 7) * 96 + (lin >> 3);
    const int mloc0 = (swz / 12) * 128;
    const int j0 = (swz % 12) * 128;
    const bool isQ = (j0 < 512);
#define SWZ(row, ks) ((row) * 64 + (((ks) ^ (((row) >> 1) & 3)) << 4))
    const int srow0 = tid >> 2;
    const int srow1 = srow0 + 64;
    const int ksw = tid & 3;
    const int ks0 = ksw ^ ((srow0 >> 1) & 3);
    const int ks1 = ksw ^ ((srow1 >> 1) & 3);
    const size_t ga0 = (size_t)(mloc0 + srow0) * DIMX + ks0 * 8;
    const size_t ga1 = (size_t)(mloc0 + srow1) * DIMX + ks1 * 8;
    const size_t gb0 = (size_t)(j0 + srow0) * DIMX + ks0 * 8;
    const size_t gb1 = (size_t)(j0 + srow1) * DIMX + ks1 * 8;
    const int lo0 = tid * 16;
    const int lo1 = 4096 + tid * 16;

    v4f acc[4][4];
    #pragma unroll
    for (int i = 0; i < 4; ++i)
        #pragma unroll
        for (int j = 0; j < 4; ++j)
            #pragma unroll
            for (int r = 0; r < 4; ++r) acc[i][j][r] = 0.0f;

    const int fm = lane & 15;
    const int fks = lane >> 4;
    int aofs[4], bofs[4];
    #pragma unroll
    for (int i = 0; i < 4; ++i) {
        const int am = wr * 64 + i * 16 + fm;
        const int bm = wc * 64 + i * 16 + fm;
        aofs[i] = SWZ(am, fks);
        bofs[i] = SWZ(bm, fks);
    }
#undef SWZ

    for (int k0 = 0; k0 < DIMX; k0 += 32) {
        __syncthreads();
        gld16(xh + ga0 + k0, (char*)Ah + lo0);
        gld16(xh + ga1 + k0, (char*)Ah + lo1);
        gld16(xm + ga0 + k0, (char*)Am + lo0);
        gld16(xm + ga1 + k0, (char*)Am + lo1);
        gld16(wh + gb0 + k0, (char*)Bh + lo0);
        gld16(wh + gb1 + k0, (char*)Bh + lo1);
        gld16(wm + gb0 + k0, (char*)Bm + lo0);
        gld16(wm + gb1 + k0, (char*)Bm + lo1);
        if (!isQ) {
            gld16(xl + ga0 + k0, (char*)Al + lo0);
            gld16(xl + ga1 + k0, (char*)Al + lo1);
            gld16(wl + gb0 + k0, (char*)Bl + lo0);
            gld16(wl + gb1 + k0, (char*)Bl + lo1);
        }
        __syncthreads();
        v8bf fah[4], fbh[4];
        #pragma unroll
        for (int i = 0; i < 4; ++i) {
            fah[i] = *(const v8bf*)((const char*)Ah + aofs[i]);
            fbh[i] = *(const v8bf*)((const char*)Bh + bofs[i]);
        }
        #pragma unroll
        for (int mi = 0; mi < 4; ++mi)
            #pragma unroll
            for (int ni = 0; ni < 4; ++ni)
                acc[mi][ni] = __builtin_amdgcn_mfma_f32_16x16x32_bf16(fah[mi], fbh[ni], acc[mi][ni], 0, 0, 0);
        v8bf fam[4], fbm[4];
        #pragma unroll
        for (int i = 0; i < 4; ++i) {
            fam[i] = *(const v8bf*)((const char*)Am + aofs[i]);
            fbm[i] = *(const v8bf*)((const char*)Bm + bofs[i]);
        }
        #pragma unroll
        for (int mi = 0; mi < 4; ++mi)
            #pragma unroll
            for (int ni = 0; ni < 4; ++ni) {
                acc[mi][ni] = __builtin_amdgcn_mfma_f32_16x16x32_bf16(fah[mi], fbm[ni], acc[mi][ni], 0, 0, 0);
                acc[mi][ni] = __builtin_amdgcn_mfma_f32_16x16x32_bf16(fam[mi], fbh[ni], acc[mi][ni], 0, 0, 0);
            }
        if (!isQ) {
            #pragma unroll
            for (int mi = 0; mi < 4; ++mi)
                #pragma unroll
                for (int ni = 0; ni < 4; ++ni)
                    acc[mi][ni] = __builtin_amdgcn_mfma_f32_16x16x32_bf16(fam[mi], fbm[ni], acc[mi][ni], 0, 0, 0);
            v8bf fal[4], fbl[4];
            #pragma unroll
            for (int i = 0; i < 4; ++i) {
                fal[i] = *(const v8bf*)((const char*)Al + aofs[i]);
                fbl[i] = *(const v8bf*)((const char*)Bl + bofs[i]);
            }
            #pragma unroll
            for (int mi = 0; mi < 4; ++mi)
                #pragma unroll
                for (int ni = 0; ni < 4; ++ni) {
                    acc[mi][ni] = __builtin_amdgcn_mfma_f32_16x16x32_bf16(fah[mi], fbl[ni], acc[mi][ni], 0, 0, 0);
                    acc[mi][ni] = __builtin_amdgcn_mfma_f32_16x16x32_bf16(fal[mi], fbh[ni], acc[mi][ni], 0, 0, 0);
                }
        }
    }
    const int crow = (lane >> 4) * 4;
    const int ccol = lane & 15;
    if (isQ) {
        #pragma unroll
        for (int mi = 0; mi < 4; ++mi)
            #pragma unroll
            for (int ni = 0; ni < 4; ++ni) {
                const int j = j0 + wc * 64 + ni * 16 + ccol;
                #pragma unroll
                for (int r = 0; r < 4; ++r) {
                    const int m = mbase + mloc0 + wr * 64 + mi * 16 + crow + r;
                    qb[(size_t)m * DIMX + j] = f2bf(acc[mi][ni][r]);
                }
            }
    } else if (j0 < 1024) {  // k -> fp32 [N][512]
        #pragma unroll
        for (int mi = 0; mi < 4; ++mi)
            #pragma unroll
            for (int ni = 0; ni < 4; ++ni) {
                const int j = j0 - 512 + wc * 64 + ni * 16 + ccol;
                #pragma unroll
                for (int r = 0; r < 4; ++r) {
                    const int m = mbase + mloc0 + wr * 64 + mi * 16 + crow + r;
                    kvb[(size_t)m * 512 + j] = acc[mi][ni][r];
                }
            }
    } else {                 // v -> hi/mid bf16 [N][512]
        #pragma unroll
        for (int mi = 0; mi < 4; ++mi)
            #pragma unroll
            for (int ni = 0; ni < 4; ++ni) {
                const int j = j0 - 1024 + wc * 64 + ni * 16 + ccol;
                #pragma unroll
                for (int r = 0; r < 4; ++r) {
                    const int m = mbase + mloc0 + wr * 64 + mi * 16 + crow + r;
                    const float val = acc[mi][ni][r];
                    const unsigned short hb = f2bf(val);
                    vhg[(size_t)m * 512 + j] = hb;
                    vmg[(size_t)m * 512 + j] = f2bf(val - bf2f(hb));
                }
            }
    }
}

// ---------------- K2: MFMA kv-aggregation (r7/r12 version) ----------------
__global__ __launch_bounds__(512, 1) void k_kvagg(
        const float* __restrict__ kvb,
        const unsigned short* __restrict__ vhg, const unsigned short* __restrict__ vmg,
        const unsigned short* __restrict__ agh, const unsigned short* __restrict__ agm,
        const unsigned short* __restrict__ agl,
        float* __restrict__ pacc, float* __restrict__ psum) {
    __shared__ __align__(16) char S[61440];
    const int h = blockIdx.x, chunk = blockIdx.y;
    const int t = threadIdx.x, lane = t & 63, w = t >> 6;
    const int fr = lane & 15, fc = lane >> 4;
    const int n0 = chunk * KVCHUNK;
    v8bf agf[3][2][2];
    #pragma unroll
    for (int mt = 0; mt < 2; ++mt)
        #pragma unroll
        for (int ks = 0; ks < 2; ++ks) {
            const size_t ix = ((size_t)(h * ANUM + w * 32 + mt * 16 + fr)) * 64 + ks * 32 + fc * 8;
            agf[0][mt][ks] = *(const v8bf*)(agh + ix);
            agf[1][mt][ks] = *(const v8bf*)(agm + ix);
            agf[2][mt][ks] = *(const v8bf*)(agl + ix);
        }
    const int cn = t >> 4;
    const int cd0 = (t & 15) * 4;
    float4 kreg; ushort4 vhr, vmr;
    {
        const size_t gix = ((size_t)(n0 + cn)) * 512 + h * 64 + cd0;
        kreg = *(const float4*)(kvb + gix);
        vhr = *(const ushort4*)(vhg + gix);
        vmr = *(const ushort4*)(vmg + gix);
    }
    v4f kvacc[2][4];
    #pragma unroll
    for (int mt = 0; mt < 2; ++mt)
        #pragma unroll
        for (int nt = 0; nt < 4; ++nt)
            #pragma unroll
            for (int r = 0; r < 4; ++r) kvacc[mt][nt][r] = 0.f;
    float sacc[2][4] = {{0.f,0.f,0.f,0.f},{0.f,0.f,0.f,0.f}};

    for (int it = 0; it < 32; ++it) {
        __syncthreads();
        {
            ushort4 H, M, L;
            unsigned short hh;
            hh = f2bf(kreg.x); { float r1 = kreg.x - bf2f(hh); M.x = f2bf(r1);
                L.x = f2bf(r1 - bf2f(M.x)); H.x = hh; }
            hh = f2bf(kreg.y); { float r1 = kreg.y - bf2f(hh); M.y = f2bf(r1);
                L.y = f2bf(r1 - bf2f(M.y)); H.y = hh; }
            hh = f2bf(kreg.z); { float r1 = kreg.z - bf2f(hh); M.z = f2bf(r1);
                L.z = f2bf(r1 - bf2f(M.z)); H.z = hh; }
            hh = f2bf(kreg.w); { float r1 = kreg.w - bf2f(hh); M.w = f2bf(r1);
                L.w = f2bf(r1 - bf2f(M.w)); H.w = hh; }
            const int kb0 = cn * 128 + ((cd0 * 2) ^ ((cn & 7) << 4));
            *(ushort4*)(S + kb0) = H;
            *(ushort4*)(S + 4096 + kb0) = M;
            *(ushort4*)(S + 8192 + kb0) = L;
            const unsigned short vh4[4] = {vhr.x, vhr.y, vhr.z, vhr.w};
            const unsigned short vm4[4] = {vmr.x, vmr.y, vmr.z, vmr.w};
            #pragma unroll
            for (int i = 0; i < 4; ++i) {
                const int d = cd0 + i;
                const int vb = d * 128 + ((cn * 2) ^ ((d & 7) << 4));
                *(unsigned short*)(S + 12288 + vb) = vh4[i];
                *(unsigned short*)(S + 20480 + vb) = vm4[i];
            }
        }
        if (it < 31) {
            const size_t gix = ((size_t)(n0 + (it + 1) * 32 + cn)) * 512 + h * 64 + cd0;
            kreg = *(const float4*)(kvb + gix);
            vhr = *(const ushort4*)(vhg + gix);
            vmr = *(const ushort4*)(vmg + gix);
        }
        __syncthreads();
        v4f C[2][2];
        #pragma unroll
        for (int mt = 0; mt < 2; ++mt)
            #pragma unroll
            for (int nt = 0; nt < 2; ++nt)
                #pragma unroll
                for (int r = 0; r < 4; ++r) C[mt][nt][r] = 0.f;
        #pragma unroll
        for (int ks = 0; ks < 2; ++ks) {
            v8bf kb[3][2];
            #pragma unroll
            for (int nt = 0; nt < 2; ++nt) {
                const int row = nt * 16 + fr;
                const int off = row * 128 + ((ks * 64 + fc * 16) ^ ((row & 7) << 4));
                kb[0][nt] = *(const v8bf*)(S + off);
                kb[1][nt] = *(const v8bf*)(S + 4096 + off);
                kb[2][nt] = *(const v8bf*)(S + 8192 + off);
            }
            #pragma unroll
            for (int mt = 0; mt < 2; ++mt)
                #pragma unroll
                for (int nt = 0; nt < 2; ++nt) {
                    C[mt][nt] = __builtin_amdgcn_mfma_f32_16x16x32_bf16(agf[0][mt][ks], kb[0][nt], C[mt][nt], 0, 0, 0);
                    C[mt][nt] = __builtin_amdgcn_mfma_f32_16x16x32_bf16(agf[0][mt][ks], kb[1][nt], C[mt][nt], 0, 0, 0);
                    C[mt][nt] = __builtin_amdgcn_mfma_f32_16x16x32_bf16(agf[1][mt][ks], kb[0][nt], C[mt][nt], 0, 0, 0);
                    C[mt][nt] = __builtin_amdgcn_mfma_f32_16x16x32_bf16(agf[1][mt][ks], kb[1][nt], C[mt][nt], 0, 0, 0);
                    C[mt][nt] = __builtin_amdgcn_mfma_f32_16x16x32_bf16(agf[0][mt][ks], kb[2][nt], C[mt][nt], 0, 0, 0);
                    C[mt][nt] = __builtin_amdgcn_mfma_f32_16x16x32_bf16(agf[2][mt][ks], kb[0][nt], C[mt][nt], 0, 0, 0);
                }
        }
        const int pbase = 28672 + w * 4096;
        #pragma unroll
        for (int mt = 0; mt < 2; ++mt) {
            float sl[4] = {0.f, 0.f, 0.f, 0.f};
            #pragma unroll
            for (int nt = 0; nt < 2; ++nt)
                #pragma unroll
                for (int r = 0; r < 4; ++r) {
                    const float pv = __expf(C[mt][nt][r] - 20.f);
                    sl[r] += pv;
                    const unsigned short ph = f2bf(pv);
                    const unsigned short pmv = f2bf(pv - bf2f(ph));
                    const int a = mt * 16 + fc * 4 + r;
                    const int off = pbase + a * 64 + (((nt * 16 + fr) * 2) ^ ((a & 3) << 4));
                    *(unsigned short*)(S + off) = ph;
                    *(unsigned short*)(S + off + 2048) = pmv;
                }
            #pragma unroll
            for (int r = 0; r < 4; ++r) {
                float v = sl[r];
                v += __shfl_xor(v, 1, 64); v += __shfl_xor(v, 2, 64);
                v += __shfl_xor(v, 4, 64); v += __shfl_xor(v, 8, 64);
                sacc[mt][r] += v;
            }
        }
        v8bf pah[2], pam[2];
        #pragma unroll
        for (int mt = 0; mt < 2; ++mt) {
            const int a = mt * 16 + fr;
            const int off = pbase + a * 64 + ((fc * 16) ^ ((a & 3) << 4));
            pah[mt] = *(const v8bf*)(S + off);
            pam[mt] = *(const v8bf*)(S + off + 2048);
        }
        #pragma unroll
        for (int nt = 0; nt < 4; ++nt) {
            const int d = nt * 16 + fr;
            const int off = 12288 + d * 128 + ((fc * 16) ^ ((d & 7) << 4));
            v8bf vbh = *(const v8bf*)(S + off);
            v8bf vbm = *(const v8bf*)(S + off + 8192);
            #pragma unroll
            for (int mt = 0; mt < 2; ++mt) {
                kvacc[mt][nt] = __builtin_amdgcn_mfma_f32_16x16x32_bf16(pah[mt], vbh, kvacc[mt][nt], 0, 0, 0);
                kvacc[mt][nt] = __builtin_amdgcn_mfma_f32_16x16x32_bf16(pah[mt], vbm, kvacc[mt][nt], 0, 0, 0);
                kvacc[mt][nt] = __builtin_amdgcn_mfma_f32_16x16x32_bf16(pam[mt], vbh, kvacc[mt][nt], 0, 0, 0);
                kvacc[mt][nt] = __builtin_amdgcn_mfma_f32_16x16x32_bf16(pam[mt], vbm, kvacc[mt][nt], 0, 0, 0);
            }
        }
    }
    const size_t base = (size_t)chunk * HEADS + h;
    #pragma unroll
    for (int mt = 0; mt < 2; ++mt)
        #pragma unroll
        for (int r = 0; r < 4; ++r)
            if (fr == 0)
                psum[base * ANUM + w * 32 + mt * 16 + fc * 4 + r] = sacc[mt][r];
    #pragma unroll
    for (int mt = 0; mt < 2; ++mt)
        #pragma unroll
        for (int nt = 0; nt < 4; ++nt)
            #pragma unroll
            for (int r = 0; r < 4; ++r)
                pacc[base * (ANUM * DHEAD) +
                     (size_t)(w * 32 + mt * 16 + fc * 4 + r) * 64 + nt * 16 + fr] =
                    kvacc[mt][nt][r];
}

// ---------------- K2b: combine chunk partials -> kv[h,a,d] ----------------
__global__ __launch_bounds__(256) void k_combine(const float* __restrict__ pacc,
                                                 const float* __restrict__ psum,
                                                 float* __restrict__ kv) {
    const int idx = blockIdx.x * 256 + threadIdx.x;
    const int ha = idx >> 6;
    float a = 0.f, s = 0.f;
    for (int c = 0; c < NCHUNK; ++c) {
        a += pacc[(size_t)c*131072 + idx];
        s += psum[c*2048 + ha];
    }
    kv[idx] = a / s;
}

// ---------------- K3a: partial dot products for thresh (128 blocks) ----------------
__global__ __launch_bounds__(256) void k_thresh_part(const float* __restrict__ kv,
                                                     const float* __restrict__ Wt,
                                                     float* __restrict__ part) {
    __shared__ float red[256];
    const int t = threadIdx.x;
    const int base = blockIdx.x * 1024 + t * 4;
    float4 kvv = *(const float4*)&kv[base];
    float4 wv  = *(const float4*)&Wt[base & (DIMX - 1)];
    red[t] = kvv.x * wv.x + kvv.y * wv.y + kvv.z * wv.z + kvv.w * wv.w;
    __syncthreads();
    for (int off = 128; off > 0; off >>= 1) {
        if (t < off) red[t] += red[t + off];
        __syncthreads();
    }
    if (t == 0) part[blockIdx.x] = red[0];
}

// ---------------- K3b: finalize thresh = sigmoid(sum/256 + bt) ----------------
__global__ __launch_bounds__(128) void k_thresh_fin(const float* __restrict__ part,
                                                    const float* __restrict__ bt,
                                                    float* __restrict__ th) {
    __shared__ float red[128];
    const int t = threadIdx.x;
    red[t] = part[t];
    __syncthreads();
    for (int off = 64; off > 0; off >>= 1) {
        if (t < off) red[t] += red[t + off];
        __syncthreads();
    }
    if (t == 0) {
        float m = red[0] / (float)ANUM + bt[0];
        th[0] = 1.f / (1.f + expf(-m));
    }
}

// ---------------- K4: gating + row softmax; writes TRANSPOSED split kvf ----------------
__global__ __launch_bounds__(64) void k_gate(const float* __restrict__ kv,
                                             const float* __restrict__ Wn,
                                             const float* __restrict__ bn,
                                             const float* __restrict__ Wm,
                                             const float* __restrict__ bm,
                                             const float* __restrict__ th,
                                             unsigned short* __restrict__ kth,
                                             unsigned short* __restrict__ ktm) {
    const int rowi = blockIdx.x;     // h*256+a
    const int d = threadIdx.x;
    __shared__ __align__(16) float r[64];
    r[d] = kv[(size_t)rowi*64 + d];
    __syncthreads();
    float sn = bn[d], sm = bm[d];
    #pragma unroll
    for (int j4 = 0; j4 < 16; ++j4) {
        float4 rr = *(const float4*)&r[j4*4];
        float4 w1 = *(const float4*)&Wn[d*64 + j4*4];
        float4 w2 = *(const float4*)&Wm[d*64 + j4*4];
        sn += rr.x*w1.x + rr.y*w1.y + rr.z*w1.z + rr.w*w1.w;
        sm += rr.x*w2.x + rr.y*w2.y + rr.z*w2.z + rr.w*w2.w;
    }
    float noise = 1.f/(1.f + __expf(-sn));
    float maskv = 1.f/(1.f + __expf(-sm));
    float tval = th[0];
    float val = r[d] * (maskv > tval ? 1.f : 0.f) + noise;
    float m = val;
    #pragma unroll
    for (int off = 32; off > 0; off >>= 1) m = fmaxf(m, __shfl_xor(m, off, 64));
    float e = __expf(val - m);
    float ssum = e;
    #pragma unroll
    for (int off = 32; off > 0; off >>= 1) ssum += __shfl_xor(ssum, off, 64);
    const float res = e / ssum;
    const int hh = rowi >> 8;
    const int a  = rowi & 255;
    unsigned short hb = f2bf(res);
    const size_t tix = ((size_t)hh * DHEAD + d) * ANUM + a;
    kth[tix] = hb;
    ktm[tix] = f2bf(res - bf2f(hb));
}

// ---------------- K5: out via MFMA; PV partitioned by d-columns (r11 version) ----------------
__global__ __launch_bounds__(256, 4) void k_out_mfma(
        const unsigned short* __restrict__ qb,
        const unsigned short* __restrict__ agh, const unsigned short* __restrict__ agm,
        const unsigned short* __restrict__ kth, const unsigned short* __restrict__ ktm,
        float* __restrict__ out) {
    __shared__ __align__(16) unsigned short P[64 * 256];    // [tok][agent] swizzled, 32KB
    __shared__ float s_red[4][64];
    const int t = threadIdx.x;
    const int lane = t & 63;
    const int w = t >> 6;
    const int h = blockIdx.y;
    const int n0 = blockIdx.x * 64;
    const int fr = lane & 15;
    const int fc = lane >> 4;
    v8bf qa[4][2];
    #pragma unroll
    for (int mt = 0; mt < 4; ++mt) {
        const unsigned short* qp = qb + (size_t)(n0 + mt * 16 + fr) * DIMX + h * DHEAD + fc * 8;
        qa[mt][0] = *(const v8bf*)qp;
        qa[mt][1] = *(const v8bf*)(qp + 32);
    }
    v4f C[4][4];
    #pragma unroll
    for (int i = 0; i < 4; ++i)
        #pragma unroll
        for (int j = 0; j < 4; ++j)
            #pragma unroll
            for (int r = 0; r < 4; ++r) C[i][j][r] = 0.f;
    const int a0w = w * 64;
    __builtin_amdgcn_s_setprio(1);
    #pragma unroll
    for (int nt = 0; nt < 4; ++nt) {
        const size_t bix = ((size_t)h * ANUM + a0w + nt * 16 + fr) * DHEAD + fc * 8;
        v8bf B0h = *(const v8bf*)(agh + bix);
        v8bf B1h = *(const v8bf*)(agh + bix + 32);
        v8bf B0m = *(const v8bf*)(agm + bix);
        v8bf B1m = *(const v8bf*)(agm + bix + 32);
        #pragma unroll
        for (int mt = 0; mt < 4; ++mt) {
            C[mt][nt] = __builtin_amdgcn_mfma_f32_16x16x32_bf16(qa[mt][0], B0h, C[mt][nt], 0, 0, 0);
            C[mt][nt] = __builtin_amdgcn_mfma_f32_16x16x32_bf16(qa[mt][1], B1h, C[mt][nt], 0, 0, 0);
            C[mt][nt] = __builtin_amdgcn_mfma_f32_16x16x32_bf16(qa[mt][0], B0m, C[mt][nt], 0, 0, 0);
            C[mt][nt] = __builtin_amdgcn_mfma_f32_16x16x32_bf16(qa[mt][1], B1m, C[mt][nt], 0, 0, 0);
        }
    }
    __builtin_amdgcn_s_setprio(0);
    #pragma unroll
    for (int mt = 0; mt < 4; ++mt)
        #pragma unroll
        for (int r = 0; r < 4; ++r) {
            const int tok = mt * 16 + fc * 4 + r;
            const int sw = (tok & 7) << 4;
            float pv[4];
            float sloc = 0.f;
            #pragma unroll
            for (int nt = 0; nt < 4; ++nt) {
                pv[nt] = __expf(C[mt][nt][r] * SCALE_Q);
                sloc += pv[nt];
            }
            #pragma unroll
            for (int m = 1; m < 16; m <<= 1) sloc += __shfl_xor(sloc, m, 64);
            if (fr == 0) s_red[w][tok] = sloc;
            #pragma unroll
            for (int nt = 0; nt < 4; ++nt) {
                const int ag = a0w + nt * 16 + fr;
                *(unsigned short*)((char*)P + ((tok * 512 + ag * 2) ^ sw)) = f2bf(pv[nt]);
            }
        }
    __syncthreads();
    v4f D[4];
    #pragma unroll
    for (int tg = 0; tg < 4; ++tg)
        #pragma unroll
        for (int r = 0; r < 4; ++r) D[tg][r] = 0.f;
    const int dcol = w * 16 + fr;
    __builtin_amdgcn_s_setprio(1);
    #pragma unroll
    for (int ks = 0; ks < 8; ++ks) {
        const size_t bix = ((size_t)h * DHEAD + dcol) * ANUM + fc * 8 + ks * 32;
        v8bf vh = *(const v8bf*)(kth + bix);
        v8bf vm = *(const v8bf*)(ktm + bix);
        #pragma unroll
        for (int tg = 0; tg < 4; ++tg) {
            const int tok = tg * 16 + fr;
            const int sw = (tok & 7) << 4;
            v8bf pa = *(const v8bf*)((const char*)P + ((tok * 512 + fc * 16 + ks * 64) ^ sw));
            D[tg] = __builtin_amdgcn_mfma_f32_16x16x32_bf16(pa, vh, D[tg], 0, 0, 0);
            D[tg] = __builtin_amdgcn_mfma_f32_16x16x32_bf16(pa, vm, D[tg], 0, 0, 0);
        }
    }
    __builtin_amdgcn_s_setprio(0);
    #pragma unroll
    for (int tg = 0; tg < 4; ++tg)
        #pragma unroll
        for (int r = 0; r < 4; ++r) {
            const int tok = tg * 16 + fc * 4 + r;
            const float inv = 1.f / (s_red[0][tok] + s_red[1][tok] + s_red[2][tok] + s_red[3][tok]);
            out[(size_t)(n0 + tok) * DIMX + h * DHEAD + dcol] = D[tg][r] * inv;
        }
}

extern "C" void kernel_launch(void* const* d_in, const int* in_sizes, int n_in,
                              void* d_out, int out_size, void* d_ws, size_t ws_size,
                              hipStream_t stream) {
    const float* x     = (const float*)d_in[0];
    const float* Wqkv  = (const float*)d_in[1];
    const float* agent = (const float*)d_in[2];
    const float* Wn    = (const float*)d_in[3];
    const float* bn    = (const float*)d_in[4];
    const float* Wm    = (const float*)d_in[5];
    const float* bm    = (const float*)d_in[6];
    const float* Wt    = (const float*)d_in[7];
    const float* bt    = (const float*)d_in[8];
    float* out = (float*)d_out;

    const size_t KB_F  = (size_t)N_TOK * 512;         // k fp32
    const size_t VB_E  = (size_t)N_TOK * 512;         // v bf16 per split
    const size_t QB_E  = (size_t)N_TOK * DIMX;
    const size_t WSP_E = (size_t)3 * DIMX * DIMX;
    const size_t XSP_E = (size_t)STRIP * DIMX;
    const size_t PACC_F = (size_t)NCHUNK * HEADS * ANUM * DHEAD;
    const size_t PSUM_F = (size_t)NCHUNK * HEADS * ANUM;
    const size_t KV_F   = (size_t)HEADS * ANUM * DHEAD;   // 131072

    char* p = (char*)d_ws;
    float* kvb = (float*)p;            p += KB_F * 4;
    unsigned short* vhg = (unsigned short*)p;  p += VB_E * 2;
    unsigned short* vmg = (unsigned short*)p;  p += VB_E * 2;
    unsigned short* qbuf = (unsigned short*)p; p += QB_E * 2;
    unsigned short* wh = (unsigned short*)p;   p += WSP_E * 2;
    unsigned short* wm = (unsigned short*)p;   p += WSP_E * 2;
    unsigned short* wl = (unsigned short*)p;   p += WSP_E * 2;
    unsigned short* xh = (unsigned short*)p;   p += XSP_E * 2;
    unsigned short* xm = (unsigned short*)p;   p += XSP_E * 2;
    unsigned short* xl = (unsigned short*)p;   p += XSP_E * 2;
    float* pacc = (float*)p;           p += PACC_F * 4;
    float* psum = (float*)p;           p += PSUM_F * 4;
    float* kv   = (float*)p;           p += KV_F * 4;
    unsigned short* agh = (unsigned short*)p;  p += KV_F * 2;
    unsigned short* agm = (unsigned short*)p;  p += KV_F * 2;
    unsigned short* agl = (unsigned short*)p;  p += KV_F * 2;
    unsigned short* kth = (unsigned short*)p;  p += KV_F * 2;
    unsigned short* ktm = (unsigned short*)p;  p += KV_F * 2;
    float* th   = (float*)p;           p += 64;
    float* thpart = (float*)p;         p += 128 * 4;
    if (ws_size < (size_t)(p - (char*)d_ws)) return;

    k_cvt3<<<384, 256, 0, stream>>>(Wqkv, wh, wm, wl, (int)(WSP_E / 8));
    k_cvt3<<<64, 256, 0, stream>>>(agent, agh, agm, agl, (int)(KV_F / 8));
    for (int s = 0; s < N_TOK / STRIP; ++s) {
        k_cvt3<<<2048, 256, 0, stream>>>(x + (size_t)s * STRIP * DIMX, xh, xm, xl,
                                         (int)(XSP_E / 8));
        k_gemm<<<768, 256, 0, stream>>>(xh, xm, xl, wh, wm, wl,
                                        qbuf, kvb, vhg, vmg, s * STRIP);
    }
    k_kvagg <<<dim3(HEADS, NCHUNK), 512, 0, stream>>>(kvb, vhg, vmg, agh, agm, agl,
                                                      pacc, psum);
    k_combine<<<512, 256, 0, stream>>>(pacc, psum, kv);
    k_thresh_part<<<128, 256, 0, stream>>>(kv, Wt, thpart);
    k_thresh_fin<<<1, 128, 0, stream>>>(thpart, bt, th);
    k_gate  <<<HEADS*ANUM, 64, 0, stream>>>(kv, Wn, bn, Wm, bm, th, kth, ktm);
    k_out_mfma<<<dim3(N_TOK/64, HEADS), 256, 0, stream>>>(qbuf, agh, agm, kth, ktm, out);
}